// Round 21
// baseline (295.464 us; speedup 1.0000x reference)
//
#include <hip/hip_runtime.h>
#include <math.h>
#include <float.h>

constexpr int NE   = 64;      // experts
constexpr int ND   = 2048;    // hidden dim
constexpr int TOPK = 8;
constexpr int TOKS = 32;      // tokens per block (lane&31)
constexpr int NWV  = 8;       // waves per block
constexpr int BLK  = NWV * 64;// 512 threads
constexpr int EPT  = 4;       // experts per thread
constexpr int KC   = 64;      // k-chunk
constexpr int NCH  = ND / KC; // 32 chunks

// Numerics contract (DO NOT CHANGE — validated in rounds 11/18):
// h @ w.T emulating OpenBLAS sgemm fp32: K=2048 in kc panels
// {384,384,384,384,256,256} (chunks of 64: 6/6/6/6/4/4); per C-element per
// panel ONE accumulator, serial fp32 FMA with k strictly ascending; panel
// sums added to C in order (__fadd_rn). Then np ufuncs:
// l = fadd(fmul(raw, cs), cb), fp32, unfused. Rank on l32, ties -> lower
// index. Softmax value outputs fp32 (2% threshold).
__global__ __launch_bounds__(BLK)
void gate_kernel(const float* __restrict__ h, const float* __restrict__ w,
                 const float* __restrict__ cs, const float* __restrict__ cb,
                 float* __restrict__ out, int T)
{
    __shared__ float smem[4160];
    float* const hbuf = smem;          // GEMM phase: [32 tok][16 slots x 4] swizzled, 8 KB
    float* const sl   = smem;          // epilogue alias: [64 e][32 t] logits
    float* const pp   = smem + 2048;   // epilogue: [32 t][64 e] swizzled unnorm probs
    float* const pinv = smem + 4096;   // epilogue: 32 floats

    const int tid  = threadIdx.x;
    const int lane = tid & 63;
    const int wv   = __builtin_amdgcn_readfirstlane(tid >> 6);
    const int t0   = blockIdx.x * TOKS;
    const int tl   = lane & 31;            // token
    const int half = lane >> 5;            // expert half
    const int eb   = wv * 8 + half * EPT;  // first of this thread's 4 experts

    // staging: thread loads 4 floats of one token row (16 thr/row -> 256B coalesced)
    const int srow = tid >> 4;        // token row 0..31
    const int sseg = tid & 15;        // k4 slot 0..15
    const float* hsrc = h + (size_t)(t0 + srow) * ND + sseg * 4;
    const int sdst = srow * 64 + ((sseg ^ (srow & 15)) << 2);   // XOR slot swizzle

    // per-thread w row pointers (2-valued per wave -> vector path, 2 lines/instr)
    const float* wq0 = w + (size_t)(eb + 0) * ND;
    const float* wq1 = w + (size_t)(eb + 1) * ND;
    const float* wq2 = w + (size_t)(eb + 2) * ND;
    const float* wq3 = w + (size_t)(eb + 3) * ND;

    float C[EPT], a[EPT];
#pragma unroll
    for (int i = 0; i < EPT; ++i) C[i] = 0.f;

    // prologue: stage chunk 0
    *reinterpret_cast<float4*>(&hbuf[sdst]) = *reinterpret_cast<const float4*>(hsrc);
    __syncthreads();

    const int rsl = tl & 15;   // read-side slot XOR

#pragma unroll 1
    for (int c = 0; c < NCH; ++c) {
        const bool pstart = (c == 0) || (c == 6) || (c == 12) || (c == 18) || (c == 24) || (c == 28);
        const bool pend   = (c == 5) || (c == 11) || (c == 17) || (c == 23) || (c == 27) || (c == 31);
        if (pstart) {
#pragma unroll
            for (int i = 0; i < EPT; ++i) a[i] = 0.f;
        }

        // prefetch next h chunk (1 float4 live through compute)
        float4 nh;
        const bool hasn = (c + 1 < NCH);
        if (hasn) nh = *reinterpret_cast<const float4*>(hsrc + (c + 1) * KC);

        // ---- compute chunk c: serial FMA, k ascending (contract) ----
#pragma unroll 2
        for (int k4 = 0; k4 < KC / 4; ++k4) {
            // one swizzled ds_read_b128: h[tl][k4*4 .. +3]
            const float4 h4 = *reinterpret_cast<const float4*>(
                                  &hbuf[tl * 64 + ((k4 ^ rsl) << 2)]);
            // w: 4 vector loads, imm offsets 0..240B (pointers advance per chunk)
            const float4 w0 = *reinterpret_cast<const float4*>(wq0 + k4 * 4);
            const float4 w1 = *reinterpret_cast<const float4*>(wq1 + k4 * 4);
            const float4 w2 = *reinterpret_cast<const float4*>(wq2 + k4 * 4);
            const float4 w3 = *reinterpret_cast<const float4*>(wq3 + k4 * 4);

            a[0] = __builtin_fmaf(h4.w, w0.w, __builtin_fmaf(h4.z, w0.z,
                   __builtin_fmaf(h4.y, w0.y, __builtin_fmaf(h4.x, w0.x, a[0]))));
            a[1] = __builtin_fmaf(h4.w, w1.w, __builtin_fmaf(h4.z, w1.z,
                   __builtin_fmaf(h4.y, w1.y, __builtin_fmaf(h4.x, w1.x, a[1]))));
            a[2] = __builtin_fmaf(h4.w, w2.w, __builtin_fmaf(h4.z, w2.z,
                   __builtin_fmaf(h4.y, w2.y, __builtin_fmaf(h4.x, w2.x, a[2]))));
            a[3] = __builtin_fmaf(h4.w, w3.w, __builtin_fmaf(h4.z, w3.z,
                   __builtin_fmaf(h4.y, w3.y, __builtin_fmaf(h4.x, w3.x, a[3]))));
        }
        wq0 += KC; wq1 += KC; wq2 += KC; wq3 += KC;

        if (pend) {
#pragma unroll
            for (int i = 0; i < EPT; ++i) C[i] = __fadd_rn(C[i], a[i]);
        }

        __syncthreads();                  // all reads of hbuf done
        if (hasn)
            *reinterpret_cast<float4*>(&hbuf[sdst]) = nh;
        __syncthreads();                  // next chunk staged
    }

    // ---- epilogue (validated structure, 32 tokens) ----
#pragma unroll
    for (int i = 0; i < EPT; ++i) {
        const int e = eb + i;
        // np ufuncs: mul then add, both rounded fp32, no fma contraction
        sl[e * TOKS + tl] = __fadd_rn(__fmul_rn(C[i], cs[e]), cb[e]);
    }
    __syncthreads();

    float* const out_probs = out;                           // T*64
    float* const out_wts   = out + (size_t)T * NE;          // T*8
    float* const out_idx   = out + (size_t)T * (NE + TOPK); // T*8

    if (wv == 0 && lane < TOKS) {
        float l[NE];
#pragma unroll
        for (int e = 0; e < NE; ++e) l[e] = sl[e * TOKS + lane];

        float m = l[0];
#pragma unroll
        for (int e = 1; e < NE; ++e) m = fmaxf(m, l[e]);

        float u[NE];
        float s = 0.f;
#pragma unroll
        for (int e = 0; e < NE; ++e) {
            u[e] = expf(l[e] - m);
            s += u[e];
        }
        const float inv = 1.f / s;
        pinv[lane] = inv;

#pragma unroll
        for (int e = 0; e < NE; ++e)
            pp[lane * NE + (e ^ lane)] = u[e];     // lane<32: e^lane bijective

        // top-8 on l32; strict > insertion, e ascending => ties keep lower index
        float kv[TOPK]; int iv[TOPK];
#pragma unroll
        for (int j = 0; j < TOPK; ++j) { kv[j] = -FLT_MAX; iv[j] = 0; }
#pragma unroll
        for (int e = 0; e < NE; ++e) {
            float v = l[e]; int ix = e;
#pragma unroll
            for (int j = 0; j < TOPK; ++j) {
                const bool gt = v > kv[j];
                const float nv = gt ? kv[j] : v;
                const int   ni = gt ? iv[j] : ix;
                kv[j] = gt ? v  : kv[j];
                iv[j] = gt ? ix : iv[j];
                v = nv; ix = ni;
            }
        }

        float ws[TOPK];
#pragma unroll
        for (int j = 0; j < TOPK; ++j)
            ws[j] = pp[lane * NE + (iv[j] ^ lane)] * inv;

        const int tok = t0 + lane;
        *reinterpret_cast<float4*>(out_wts + (size_t)tok * TOPK)
            = make_float4(ws[0], ws[1], ws[2], ws[3]);
        *reinterpret_cast<float4*>(out_wts + (size_t)tok * TOPK + 4)
            = make_float4(ws[4], ws[5], ws[6], ws[7]);
        *reinterpret_cast<float4*>(out_idx + (size_t)tok * TOPK)
            = make_float4((float)iv[0], (float)iv[1], (float)iv[2], (float)iv[3]);
        *reinterpret_cast<float4*>(out_idx + (size_t)tok * TOPK + 4)
            = make_float4((float)iv[4], (float)iv[5], (float)iv[6], (float)iv[7]);
    }
    __syncthreads();

    // cooperative coalesced probs store: 2048 floats / 512 threads = 4 each
    {
        const size_t base = (size_t)t0 * NE;
#pragma unroll
        for (int r = 0; r < (TOKS * NE) / BLK; ++r) {
            const int idx = r * BLK + tid;
            const int t = idx >> 6, e = idx & 63;
            out_probs[base + idx] = pp[t * NE + (e ^ t)] * pinv[t];
        }
    }
}

extern "C" void kernel_launch(void* const* d_in, const int* in_sizes, int n_in,
                              void* d_out, int out_size, void* d_ws, size_t ws_size,
                              hipStream_t stream)
{
    const float* h  = (const float*)d_in[0];
    const float* w  = (const float*)d_in[1];
    const float* cs = (const float*)d_in[2];
    const float* cb = (const float*)d_in[3];
    float* outp = (float*)d_out;
    const int T = in_sizes[0] / ND;   // 16384 tokens

    dim3 grid(T / TOKS);              // 512 blocks (2 per CU)
    dim3 block(BLK);                  // 512 threads, 8 waves
    hipLaunchKernelGGL(gate_kernel, grid, block, 0, stream,
                       h, w, cs, cb, outp, T);
}

// Round 22
// 98.537 us; speedup vs baseline: 2.9985x; 2.9985x over previous
//
#include <hip/hip_runtime.h>
#include <math.h>
#include <float.h>

constexpr int NE   = 64;      // experts
constexpr int ND   = 2048;    // hidden dim
constexpr int TOPK = 8;
constexpr int TOKS = 64;      // tokens per tile (= lanes)
constexpr int NWV  = 8;       // waves per block
constexpr int BLK  = NWV * 64;// 512 threads
constexpr int EPW  = NE / NWV;// 8 experts per wave
constexpr int KC   = 64;      // k-chunk
constexpr int NCH  = ND / KC; // 32 chunks
constexpr int HSTR = 65;      // h LDS row stride (+1 pad)
constexpr int NPAN = 6;       // OpenBLAS kc panels {384,384,384,384,256,256}

// Numerics contract (DO NOT CHANGE — validated rounds 11/18):
// per C-element per panel ONE accumulator, serial fp32 FMA, k ascending;
// panel sums combined in order p0..p5 with __fadd_rn. Then np ufuncs:
// l = fadd(fmul(raw, cs), cb), fp32, unfused. Rank on l32, ties -> lower.

// ---------- Phase 1: one kc-panel per block, write panel accumulator ----------
__global__ __launch_bounds__(BLK)
void gemm_panel_kernel(const float* __restrict__ h, const float* __restrict__ w,
                       float* __restrict__ wsp, int T)
{
    __shared__ float hbuf[KC * HSTR];  // 16.6 KB only -> 4+ blocks/CU

    const int tid  = threadIdx.x;
    const int lane = tid & 63;                       // lane = token
    const int wv   = __builtin_amdgcn_readfirstlane(tid >> 6);
    const int tile = blockIdx.x;
    const int pan  = blockIdx.y;
    const int t0   = tile * TOKS;
    const int e0   = wv * EPW;
    const int c0   = (pan < 4) ? pan * 6 : 24 + (pan - 4) * 4;
    const int c1   = c0 + ((pan < 4) ? 6 : 4);

    const int srow = tid >> 3;        // token row
    const int sseg = tid & 7;         // 8-float k segment
    const float* hsrc = h + (size_t)(t0 + srow) * ND + sseg * 8;

    float a[EPW];
#pragma unroll
    for (int i = 0; i < EPW; ++i) a[i] = 0.f;

    // stage first chunk of this panel
    {
        const float4 v0 = *reinterpret_cast<const float4*>(hsrc + c0 * KC);
        const float4 v1 = *reinterpret_cast<const float4*>(hsrc + c0 * KC + 4);
        const float vv[8] = {v0.x, v0.y, v0.z, v0.w, v1.x, v1.y, v1.z, v1.w};
#pragma unroll
        for (int j = 0; j < 8; ++j)
            hbuf[(sseg * 8 + j) * HSTR + srow] = vv[j];
    }
    __syncthreads();

#pragma unroll 1
    for (int c = c0; c < c1; ++c) {
        float4 n0, n1;
        const bool hasn = (c + 1 < c1);
        if (hasn) {
            n0 = *reinterpret_cast<const float4*>(hsrc + (c + 1) * KC);
            n1 = *reinterpret_cast<const float4*>(hsrc + (c + 1) * KC + 4);
        }

        const int kb = c * KC;
#pragma unroll 2
        for (int k4 = 0; k4 < KC / 4; ++k4) {
            const float h0 = hbuf[(k4 * 4 + 0) * HSTR + lane];
            const float h1 = hbuf[(k4 * 4 + 1) * HSTR + lane];
            const float h2 = hbuf[(k4 * 4 + 2) * HSTR + lane];
            const float h3 = hbuf[(k4 * 4 + 3) * HSTR + lane];

#pragma unroll
            for (int i = 0; i < EPW; ++i) {
                const float* wp = w + (size_t)(e0 + i) * ND + kb + k4 * 4; // uniform -> s_load
                float t = a[i];
                t = __builtin_fmaf(h0, wp[0], t);
                t = __builtin_fmaf(h1, wp[1], t);
                t = __builtin_fmaf(h2, wp[2], t);
                t = __builtin_fmaf(h3, wp[3], t);
                a[i] = t;
            }
        }

        __syncthreads();
        if (hasn) {
            const float vv[8] = {n0.x, n0.y, n0.z, n0.w, n1.x, n1.y, n1.z, n1.w};
#pragma unroll
            for (int j = 0; j < 8; ++j)
                hbuf[(sseg * 8 + j) * HSTR + srow] = vv[j];
        }
        __syncthreads();
    }

    // write panel partials: ws[((pan*NT + tile)*NE + e)*TOKS + t] (coalesced)
    const int NT = T / TOKS;
    float* dst = wsp + (((size_t)pan * NT + tile) * NE) * TOKS;
#pragma unroll
    for (int i = 0; i < EPW; ++i)
        dst[(e0 + i) * TOKS + lane] = a[i];
}

// ---------- Phase 2: in-order panel combine + validated epilogue ----------
__global__ __launch_bounds__(BLK)
void combine_kernel(const float* __restrict__ wsp,
                    const float* __restrict__ cs, const float* __restrict__ cb,
                    float* __restrict__ out, int T)
{
    __shared__ float sl[NE * TOKS];
    __shared__ float pp[TOKS * NE];
    __shared__ float pinv[TOKS];

    const int tid  = threadIdx.x;
    const int lane = tid & 63;
    const int wv   = __builtin_amdgcn_readfirstlane(tid >> 6);
    const int tile = blockIdx.x;
    const int t0   = tile * TOKS;
    const int e0   = wv * EPW;
    const int NT   = T / TOKS;
    const size_t pstr = (size_t)NT * NE * TOKS;

#pragma unroll
    for (int i = 0; i < EPW; ++i) {
        const int e = e0 + i;
        const float* src = wsp + ((size_t)tile * NE + e) * TOKS + lane;
        // combine in order: ((((a0+a1)+a2)+a3)+a4)+a5  (contract)
        float C = src[0];
        C = __fadd_rn(C, src[pstr]);
        C = __fadd_rn(C, src[2 * pstr]);
        C = __fadd_rn(C, src[3 * pstr]);
        C = __fadd_rn(C, src[4 * pstr]);
        C = __fadd_rn(C, src[5 * pstr]);
        // np ufuncs: mul then add, both rounded fp32, no fma contraction
        sl[e * TOKS + lane] = __fadd_rn(__fmul_rn(C, cs[e]), cb[e]);
    }
    __syncthreads();

    float* const out_probs = out;
    float* const out_wts   = out + (size_t)T * NE;
    float* const out_idx   = out + (size_t)T * (NE + TOPK);

    if (wv == 0) {
        float l[NE];
#pragma unroll
        for (int e = 0; e < NE; ++e) l[e] = sl[e * TOKS + lane];

        float m = l[0];
#pragma unroll
        for (int e = 1; e < NE; ++e) m = fmaxf(m, l[e]);

        float u[NE];
        float s = 0.f;
#pragma unroll
        for (int e = 0; e < NE; ++e) {
            u[e] = expf(l[e] - m);
            s += u[e];
        }
        const float inv = 1.f / s;
        pinv[lane] = inv;

#pragma unroll
        for (int e = 0; e < NE; ++e)
            pp[lane * NE + (e ^ (lane & 31))] = u[e];

        // top-8 on l32; strict > insertion => ties keep lower index
        float kv[TOPK]; int iv[TOPK];
#pragma unroll
        for (int j = 0; j < TOPK; ++j) { kv[j] = -FLT_MAX; iv[j] = 0; }
#pragma unroll
        for (int e = 0; e < NE; ++e) {
            float v = l[e]; int ix = e;
#pragma unroll
            for (int j = 0; j < TOPK; ++j) {
                const bool gt = v > kv[j];
                const float nv = gt ? kv[j] : v;
                const int   ni = gt ? iv[j] : ix;
                kv[j] = gt ? v  : kv[j];
                iv[j] = gt ? ix : iv[j];
                v = nv; ix = ni;
            }
        }

        float ws0[TOPK];
#pragma unroll
        for (int j = 0; j < TOPK; ++j)
            ws0[j] = pp[lane * NE + (iv[j] ^ (lane & 31))] * inv;

        const int tok = t0 + lane;
        *reinterpret_cast<float4*>(out_wts + (size_t)tok * TOPK)
            = make_float4(ws0[0], ws0[1], ws0[2], ws0[3]);
        *reinterpret_cast<float4*>(out_wts + (size_t)tok * TOPK + 4)
            = make_float4(ws0[4], ws0[5], ws0[6], ws0[7]);
        *reinterpret_cast<float4*>(out_idx + (size_t)tok * TOPK)
            = make_float4((float)iv[0], (float)iv[1], (float)iv[2], (float)iv[3]);
        *reinterpret_cast<float4*>(out_idx + (size_t)tok * TOPK + 4)
            = make_float4((float)iv[4], (float)iv[5], (float)iv[6], (float)iv[7]);
    }
    __syncthreads();

    {
        const size_t base = (size_t)t0 * NE;
#pragma unroll
        for (int r = 0; r < (TOKS * NE) / BLK; ++r) {
            const int idx = r * BLK + tid;
            const int t = idx >> 6, e = idx & 63;
            out_probs[base + idx] = pp[t * NE + (e ^ (t & 31))] * pinv[t];
        }
    }
}

// ---------- Fallback: R18 single kernel (152us, validated) ----------
__global__ __launch_bounds__(BLK)
void gate_single_kernel(const float* __restrict__ h, const float* __restrict__ w,
                        const float* __restrict__ cs, const float* __restrict__ cb,
                        float* __restrict__ out, int T)
{
    __shared__ float hbuf[KC * HSTR];
    __shared__ float sl[NE * TOKS];
    __shared__ float pp[TOKS * NE];
    __shared__ float pinv[TOKS];

    const int tid  = threadIdx.x;
    const int lane = tid & 63;
    const int wv   = __builtin_amdgcn_readfirstlane(tid >> 6);
    const int t0   = blockIdx.x * TOKS;
    const int e0   = wv * EPW;

    const int srow = tid >> 3;
    const int sseg = tid & 7;
    const float* hsrc = h + (size_t)(t0 + srow) * ND + sseg * 8;

    float C[EPW], a[EPW];
#pragma unroll
    for (int i = 0; i < EPW; ++i) C[i] = 0.f;

    {
        const float4 v0 = *reinterpret_cast<const float4*>(hsrc);
        const float4 v1 = *reinterpret_cast<const float4*>(hsrc + 4);
        const float vv[8] = {v0.x, v0.y, v0.z, v0.w, v1.x, v1.y, v1.z, v1.w};
#pragma unroll
        for (int j = 0; j < 8; ++j)
            hbuf[(sseg * 8 + j) * HSTR + srow] = vv[j];
    }
    __syncthreads();

#pragma unroll 1
    for (int c = 0; c < NCH; ++c) {
        const bool pstart = (c == 0) || (c == 6) || (c == 12) || (c == 18) || (c == 24) || (c == 28);
        const bool pend   = (c == 5) || (c == 11) || (c == 17) || (c == 23) || (c == 27) || (c == 31);
        if (pstart) {
#pragma unroll
            for (int i = 0; i < EPW; ++i) a[i] = 0.f;
        }
        float4 n0, n1;
        const bool hasn = (c + 1 < NCH);
        if (hasn) {
            n0 = *reinterpret_cast<const float4*>(hsrc + (c + 1) * KC);
            n1 = *reinterpret_cast<const float4*>(hsrc + (c + 1) * KC + 4);
        }
        const int kb = c * KC;
#pragma unroll 2
        for (int k4 = 0; k4 < KC / 4; ++k4) {
            const float h0 = hbuf[(k4 * 4 + 0) * HSTR + lane];
            const float h1 = hbuf[(k4 * 4 + 1) * HSTR + lane];
            const float h2 = hbuf[(k4 * 4 + 2) * HSTR + lane];
            const float h3 = hbuf[(k4 * 4 + 3) * HSTR + lane];
#pragma unroll
            for (int i = 0; i < EPW; ++i) {
                const float* wp = w + (size_t)(e0 + i) * ND + kb + k4 * 4;
                float t = a[i];
                t = __builtin_fmaf(h0, wp[0], t);
                t = __builtin_fmaf(h1, wp[1], t);
                t = __builtin_fmaf(h2, wp[2], t);
                t = __builtin_fmaf(h3, wp[3], t);
                a[i] = t;
            }
        }
        if (pend) {
#pragma unroll
            for (int i = 0; i < EPW; ++i) C[i] = __fadd_rn(C[i], a[i]);
        }
        __syncthreads();
        if (hasn) {
            const float vv[8] = {n0.x, n0.y, n0.z, n0.w, n1.x, n1.y, n1.z, n1.w};
#pragma unroll
            for (int j = 0; j < 8; ++j)
                hbuf[(sseg * 8 + j) * HSTR + srow] = vv[j];
        }
        __syncthreads();
    }

#pragma unroll
    for (int i = 0; i < EPW; ++i) {
        const int e = e0 + i;
        sl[e * TOKS + lane] = __fadd_rn(__fmul_rn(C[i], cs[e]), cb[e]);
    }
    __syncthreads();

    float* const out_probs = out;
    float* const out_wts   = out + (size_t)T * NE;
    float* const out_idx   = out + (size_t)T * (NE + TOPK);

    if (wv == 0) {
        float l[NE];
#pragma unroll
        for (int e = 0; e < NE; ++e) l[e] = sl[e * TOKS + lane];
        float m = l[0];
#pragma unroll
        for (int e = 1; e < NE; ++e) m = fmaxf(m, l[e]);
        float u[NE];
        float s = 0.f;
#pragma unroll
        for (int e = 0; e < NE; ++e) { u[e] = expf(l[e] - m); s += u[e]; }
        const float inv = 1.f / s;
        pinv[lane] = inv;
#pragma unroll
        for (int e = 0; e < NE; ++e)
            pp[lane * NE + (e ^ (lane & 31))] = u[e];
        float kv[TOPK]; int iv[TOPK];
#pragma unroll
        for (int j = 0; j < TOPK; ++j) { kv[j] = -FLT_MAX; iv[j] = 0; }
#pragma unroll
        for (int e = 0; e < NE; ++e) {
            float v = l[e]; int ix = e;
#pragma unroll
            for (int j = 0; j < TOPK; ++j) {
                const bool gt = v > kv[j];
                const float nv = gt ? kv[j] : v;
                const int   ni = gt ? iv[j] : ix;
                kv[j] = gt ? v  : kv[j];
                iv[j] = gt ? ix : iv[j];
                v = nv; ix = ni;
            }
        }
        float ws0[TOPK];
#pragma unroll
        for (int j = 0; j < TOPK; ++j)
            ws0[j] = pp[lane * NE + (iv[j] ^ (lane & 31))] * inv;
        const int tok = t0 + lane;
        *reinterpret_cast<float4*>(out_wts + (size_t)tok * TOPK)
            = make_float4(ws0[0], ws0[1], ws0[2], ws0[3]);
        *reinterpret_cast<float4*>(out_wts + (size_t)tok * TOPK + 4)
            = make_float4(ws0[4], ws0[5], ws0[6], ws0[7]);
        *reinterpret_cast<float4*>(out_idx + (size_t)tok * TOPK)
            = make_float4((float)iv[0], (float)iv[1], (float)iv[2], (float)iv[3]);
        *reinterpret_cast<float4*>(out_idx + (size_t)tok * TOPK + 4)
            = make_float4((float)iv[4], (float)iv[5], (float)iv[6], (float)iv[7]);
    }
    __syncthreads();
    {
        const size_t base = (size_t)t0 * NE;
#pragma unroll
        for (int r = 0; r < (TOKS * NE) / BLK; ++r) {
            const int idx = r * BLK + tid;
            const int t = idx >> 6, e = idx & 63;
            out_probs[base + idx] = pp[t * NE + (e ^ (t & 31))] * pinv[t];
        }
    }
}

extern "C" void kernel_launch(void* const* d_in, const int* in_sizes, int n_in,
                              void* d_out, int out_size, void* d_ws, size_t ws_size,
                              hipStream_t stream)
{
    const float* h  = (const float*)d_in[0];
    const float* w  = (const float*)d_in[1];
    const float* cs = (const float*)d_in[2];
    const float* cb = (const float*)d_in[3];
    float* outp = (float*)d_out;
    const int T = in_sizes[0] / ND;   // 16384 tokens

    const size_t need = (size_t)NPAN * T * NE * sizeof(float);  // 25.2 MB

    if (ws_size >= need) {
        float* wsp = (float*)d_ws;
        dim3 g1(T / TOKS, NPAN);      // 256 x 6 = 1536 blocks
        hipLaunchKernelGGL(gemm_panel_kernel, g1, dim3(BLK), 0, stream,
                           h, w, wsp, T);
        hipLaunchKernelGGL(combine_kernel, dim3(T / TOKS), dim3(BLK), 0, stream,
                           wsp, cs, cb, outp, T);
    } else {
        hipLaunchKernelGGL(gate_single_kernel, dim3(T / TOKS), dim3(BLK), 0, stream,
                           h, w, cs, cb, outp, T);
    }
}

// Round 23
// 70.727 us; speedup vs baseline: 4.1775x; 1.3932x over previous
//
#include <hip/hip_runtime.h>
#include <math.h>
#include <float.h>

constexpr int NE   = 64;      // experts
constexpr int ND   = 2048;    // hidden dim
constexpr int TOPK = 8;
constexpr int NWV  = 8;       // waves per block
constexpr int BLK  = NWV * 64;// 512 threads
constexpr int EPW  = NE / NWV;// 8 experts per wave
constexpr int NPAN = 6;       // OpenBLAS kc panels {384,384,384,384,256,256}

// ---- phase 1 geometry: 128-token tiles, 2 tokens/thread, KC=32 ----
constexpr int TT   = 128;     // tokens per phase-1 block
constexpr int KC1  = 32;      // k-chunk
constexpr int HST  = 129;     // [k][t] row stride (+1 pad: (k+t)%32 banks, free)

// Numerics contract (DO NOT CHANGE — validated rounds 11/18/22):
// per C-element per kc-panel ONE accumulator, serial fp32 FMA, k ascending;
// panel sums combined in order p0..p5 with __fadd_rn. Then np ufuncs:
// l = fadd(fmul(raw, cs), cb), fp32, unfused. Rank on l32, ties -> lower.

// ---------- Phase 1: one kc-panel per block, 128 tokens, 2 tok/thread ----------
__global__ __launch_bounds__(BLK)
void gemm_panel_kernel(const float* __restrict__ h, const float* __restrict__ w,
                       float* __restrict__ wsp, int T)
{
    __shared__ float hbuf[2][KC1 * HST];   // 2 x 16.5 KB double buffer

    const int tid  = threadIdx.x;
    const int lane = tid & 63;
    const int wv   = __builtin_amdgcn_readfirstlane(tid >> 6);
    const int tile = blockIdx.x;           // 128-token tile
    const int pan  = blockIdx.y;
    const int t0   = tile * TT;
    const int e0   = wv * EPW;
    // panel boundaries in KC1 chunks: {12,12,12,12,8,8}
    const int c0   = (pan < 4) ? pan * 12 : 48 + (pan - 4) * 8;
    const int c1   = c0 + ((pan < 4) ? 12 : 8);

    // staging: thread loads 8 floats of one token row (4 threads span 32 k)
    const int srow = tid >> 2;             // token row 0..127
    const int sk8  = (tid & 3) * 8;        // k offset within chunk
    const float* hsrc = h + (size_t)(t0 + srow) * ND + sk8;

    float a[EPW][2];
#pragma unroll
    for (int i = 0; i < EPW; ++i) { a[i][0] = 0.f; a[i][1] = 0.f; }

    // stage first chunk of this panel into buffer 0
    {
        const float4 v0 = *reinterpret_cast<const float4*>(hsrc + c0 * KC1);
        const float4 v1 = *reinterpret_cast<const float4*>(hsrc + c0 * KC1 + 4);
        const float vv[8] = {v0.x, v0.y, v0.z, v0.w, v1.x, v1.y, v1.z, v1.w};
#pragma unroll
        for (int j = 0; j < 8; ++j)
            hbuf[0][(sk8 + j) * HST + srow] = vv[j];
    }
    __syncthreads();

#pragma unroll 1
    for (int c = c0; c < c1; ++c) {
        const int buf = (c - c0) & 1;
        float4 n0, n1;
        const bool hasn = (c + 1 < c1);
        if (hasn) {
            n0 = *reinterpret_cast<const float4*>(hsrc + (c + 1) * KC1);
            n1 = *reinterpret_cast<const float4*>(hsrc + (c + 1) * KC1 + 4);
        }

        const int kb = c * KC1;
#pragma unroll 2
        for (int k4 = 0; k4 < KC1 / 4; ++k4) {
            // h for 2 tokens: 8 conflict-free ds_read_b32
            const float* hb = &hbuf[buf][(k4 * 4) * HST];
            const float hA0 = hb[0 * HST + lane];
            const float hA1 = hb[1 * HST + lane];
            const float hA2 = hb[2 * HST + lane];
            const float hA3 = hb[3 * HST + lane];
            const float hB0 = hb[0 * HST + lane + 64];
            const float hB1 = hb[1 * HST + lane + 64];
            const float hB2 = hb[2 * HST + lane + 64];
            const float hB3 = hb[3 * HST + lane + 64];

#pragma unroll
            for (int i = 0; i < EPW; ++i) {
                const float* wp = w + (size_t)(e0 + i) * ND + kb + k4 * 4; // uniform -> s_load
                const float w0 = wp[0], w1 = wp[1], w2 = wp[2], w3 = wp[3];
                // serial fp32 FMA, k strictly ascending (contract), per (e,tok)
                float tA = a[i][0];
                tA = __builtin_fmaf(hA0, w0, tA);
                tA = __builtin_fmaf(hA1, w1, tA);
                tA = __builtin_fmaf(hA2, w2, tA);
                tA = __builtin_fmaf(hA3, w3, tA);
                a[i][0] = tA;
                float tB = a[i][1];
                tB = __builtin_fmaf(hB0, w0, tB);
                tB = __builtin_fmaf(hB1, w1, tB);
                tB = __builtin_fmaf(hB2, w2, tB);
                tB = __builtin_fmaf(hB3, w3, tB);
                a[i][1] = tB;
            }
        }

        if (hasn) {
            const float vv[8] = {n0.x, n0.y, n0.z, n0.w, n1.x, n1.y, n1.z, n1.w};
            float* nb = &hbuf[buf ^ 1][0];
#pragma unroll
            for (int j = 0; j < 8; ++j)
                nb[(sk8 + j) * HST + srow] = vv[j];
        }
        __syncthreads();   // staged (and all reads of current buf complete)
    }

    // write panel partials per 64-token sub-tile (phase-2 layout, coalesced)
    const int NT = T / 64;
    float* dstA = wsp + (((size_t)pan * NT + tile * 2 + 0) * NE) * 64;
    float* dstB = wsp + (((size_t)pan * NT + tile * 2 + 1) * NE) * 64;
#pragma unroll
    for (int i = 0; i < EPW; ++i) {
        dstA[(e0 + i) * 64 + lane] = a[i][0];
        dstB[(e0 + i) * 64 + lane] = a[i][1];
    }
}

// ---------- Phase 2: in-order panel combine + validated epilogue ----------
__global__ __launch_bounds__(BLK)
void combine_kernel(const float* __restrict__ wsp,
                    const float* __restrict__ cs, const float* __restrict__ cb,
                    float* __restrict__ out, int T)
{
    __shared__ float sl[NE * 64];
    __shared__ float pp[64 * NE];
    __shared__ float pinv[64];

    const int tid  = threadIdx.x;
    const int lane = tid & 63;
    const int wv   = __builtin_amdgcn_readfirstlane(tid >> 6);
    const int tile = blockIdx.x;
    const int t0   = tile * 64;
    const int e0   = wv * EPW;
    const int NT   = T / 64;
    const size_t pstr = (size_t)NT * NE * 64;

#pragma unroll
    for (int i = 0; i < EPW; ++i) {
        const int e = e0 + i;
        const float* src = wsp + ((size_t)tile * NE + e) * 64 + lane;
        // combine in order: ((((a0+a1)+a2)+a3)+a4)+a5  (contract)
        float C = src[0];
        C = __fadd_rn(C, src[pstr]);
        C = __fadd_rn(C, src[2 * pstr]);
        C = __fadd_rn(C, src[3 * pstr]);
        C = __fadd_rn(C, src[4 * pstr]);
        C = __fadd_rn(C, src[5 * pstr]);
        // np ufuncs: mul then add, both rounded fp32, no fma contraction
        sl[e * 64 + lane] = __fadd_rn(__fmul_rn(C, cs[e]), cb[e]);
    }
    __syncthreads();

    float* const out_probs = out;
    float* const out_wts   = out + (size_t)T * NE;
    float* const out_idx   = out + (size_t)T * (NE + TOPK);

    if (wv == 0) {
        float l[NE];
#pragma unroll
        for (int e = 0; e < NE; ++e) l[e] = sl[e * 64 + lane];

        float m = l[0];
#pragma unroll
        for (int e = 1; e < NE; ++e) m = fmaxf(m, l[e]);

        float u[NE];
        float s = 0.f;
#pragma unroll
        for (int e = 0; e < NE; ++e) {
            u[e] = expf(l[e] - m);
            s += u[e];
        }
        const float inv = 1.f / s;
        pinv[lane] = inv;

#pragma unroll
        for (int e = 0; e < NE; ++e)
            pp[lane * NE + (e ^ (lane & 31))] = u[e];

        // top-8 on l32; strict > insertion => ties keep lower index
        float kv[TOPK]; int iv[TOPK];
#pragma unroll
        for (int j = 0; j < TOPK; ++j) { kv[j] = -FLT_MAX; iv[j] = 0; }
#pragma unroll
        for (int e = 0; e < NE; ++e) {
            float v = l[e]; int ix = e;
#pragma unroll
            for (int j = 0; j < TOPK; ++j) {
                const bool gt = v > kv[j];
                const float nv = gt ? kv[j] : v;
                const int   ni = gt ? iv[j] : ix;
                kv[j] = gt ? v  : kv[j];
                iv[j] = gt ? ix : iv[j];
                v = nv; ix = ni;
            }
        }

        float ws0[TOPK];
#pragma unroll
        for (int j = 0; j < TOPK; ++j)
            ws0[j] = pp[lane * NE + (iv[j] ^ (lane & 31))] * inv;

        const int tok = t0 + lane;
        *reinterpret_cast<float4*>(out_wts + (size_t)tok * TOPK)
            = make_float4(ws0[0], ws0[1], ws0[2], ws0[3]);
        *reinterpret_cast<float4*>(out_wts + (size_t)tok * TOPK + 4)
            = make_float4(ws0[4], ws0[5], ws0[6], ws0[7]);
        *reinterpret_cast<float4*>(out_idx + (size_t)tok * TOPK)
            = make_float4((float)iv[0], (float)iv[1], (float)iv[2], (float)iv[3]);
        *reinterpret_cast<float4*>(out_idx + (size_t)tok * TOPK + 4)
            = make_float4((float)iv[4], (float)iv[5], (float)iv[6], (float)iv[7]);
    }
    __syncthreads();

    {
        const size_t base = (size_t)t0 * NE;
#pragma unroll
        for (int r = 0; r < (64 * NE) / BLK; ++r) {
            const int idx = r * BLK + tid;
            const int t = idx >> 6, e = idx & 63;
            out_probs[base + idx] = pp[t * NE + (e ^ (t & 31))] * pinv[t];
        }
    }
}

// ---------- Fallback: R18 single kernel (152us, validated) ----------
constexpr int KCF  = 64;
constexpr int HSTF = 65;
__global__ __launch_bounds__(BLK)
void gate_single_kernel(const float* __restrict__ h, const float* __restrict__ w,
                        const float* __restrict__ cs, const float* __restrict__ cb,
                        float* __restrict__ out, int T)
{
    __shared__ float hbuf[KCF * HSTF];
    __shared__ float sl[NE * 64];
    __shared__ float pp[64 * NE];
    __shared__ float pinv[64];

    const int tid  = threadIdx.x;
    const int lane = tid & 63;
    const int wv   = __builtin_amdgcn_readfirstlane(tid >> 6);
    const int t0   = blockIdx.x * 64;
    const int e0   = wv * EPW;

    const int srow = tid >> 3;
    const int sseg = tid & 7;
    const float* hsrc = h + (size_t)(t0 + srow) * ND + sseg * 8;

    float C[EPW], a[EPW];
#pragma unroll
    for (int i = 0; i < EPW; ++i) C[i] = 0.f;

    {
        const float4 v0 = *reinterpret_cast<const float4*>(hsrc);
        const float4 v1 = *reinterpret_cast<const float4*>(hsrc + 4);
        const float vv[8] = {v0.x, v0.y, v0.z, v0.w, v1.x, v1.y, v1.z, v1.w};
#pragma unroll
        for (int j = 0; j < 8; ++j)
            hbuf[(sseg * 8 + j) * HSTF + srow] = vv[j];
    }
    __syncthreads();

#pragma unroll 1
    for (int c = 0; c < ND / KCF; ++c) {
        const bool pstart = (c == 0) || (c == 6) || (c == 12) || (c == 18) || (c == 24) || (c == 28);
        const bool pend   = (c == 5) || (c == 11) || (c == 17) || (c == 23) || (c == 27) || (c == 31);
        if (pstart) {
#pragma unroll
            for (int i = 0; i < EPW; ++i) a[i] = 0.f;
        }
        float4 n0, n1;
        const bool hasn = (c + 1 < ND / KCF);
        if (hasn) {
            n0 = *reinterpret_cast<const float4*>(hsrc + (c + 1) * KCF);
            n1 = *reinterpret_cast<const float4*>(hsrc + (c + 1) * KCF + 4);
        }
        const int kb = c * KCF;
#pragma unroll 2
        for (int k4 = 0; k4 < KCF / 4; ++k4) {
            const float h0 = hbuf[(k4 * 4 + 0) * HSTF + lane];
            const float h1 = hbuf[(k4 * 4 + 1) * HSTF + lane];
            const float h2 = hbuf[(k4 * 4 + 2) * HSTF + lane];
            const float h3 = hbuf[(k4 * 4 + 3) * HSTF + lane];
#pragma unroll
            for (int i = 0; i < EPW; ++i) {
                const float* wp = w + (size_t)(e0 + i) * ND + kb + k4 * 4;
                float t = a[i];
                t = __builtin_fmaf(h0, wp[0], t);
                t = __builtin_fmaf(h1, wp[1], t);
                t = __builtin_fmaf(h2, wp[2], t);
                t = __builtin_fmaf(h3, wp[3], t);
                a[i] = t;
            }
        }
        if (pend) {
#pragma unroll
            for (int i = 0; i < EPW; ++i) C[i] = __fadd_rn(C[i], a[i]);
        }
        __syncthreads();
        if (hasn) {
            const float vv[8] = {n0.x, n0.y, n0.z, n0.w, n1.x, n1.y, n1.z, n1.w};
#pragma unroll
            for (int j = 0; j < 8; ++j)
                hbuf[(sseg * 8 + j) * HSTF + srow] = vv[j];
        }
        __syncthreads();
    }

#pragma unroll
    for (int i = 0; i < EPW; ++i) {
        const int e = e0 + i;
        sl[e * 64 + lane] = __fadd_rn(__fmul_rn(C[i], cs[e]), cb[e]);
    }
    __syncthreads();

    float* const out_probs = out;
    float* const out_wts   = out + (size_t)T * NE;
    float* const out_idx   = out + (size_t)T * (NE + TOPK);

    if (wv == 0) {
        float l[NE];
#pragma unroll
        for (int e = 0; e < NE; ++e) l[e] = sl[e * 64 + lane];
        float m = l[0];
#pragma unroll
        for (int e = 1; e < NE; ++e) m = fmaxf(m, l[e]);
        float u[NE];
        float s = 0.f;
#pragma unroll
        for (int e = 0; e < NE; ++e) { u[e] = expf(l[e] - m); s += u[e]; }
        const float inv = 1.f / s;
        pinv[lane] = inv;
#pragma unroll
        for (int e = 0; e < NE; ++e)
            pp[lane * NE + (e ^ (lane & 31))] = u[e];
        float kv[TOPK]; int iv[TOPK];
#pragma unroll
        for (int j = 0; j < TOPK; ++j) { kv[j] = -FLT_MAX; iv[j] = 0; }
#pragma unroll
        for (int e = 0; e < NE; ++e) {
            float v = l[e]; int ix = e;
#pragma unroll
            for (int j = 0; j < TOPK; ++j) {
                const bool gt = v > kv[j];
                const float nv = gt ? kv[j] : v;
                const int   ni = gt ? iv[j] : ix;
                kv[j] = gt ? v  : kv[j];
                iv[j] = gt ? ix : iv[j];
                v = nv; ix = ni;
            }
        }
        float ws0[TOPK];
#pragma unroll
        for (int j = 0; j < TOPK; ++j)
            ws0[j] = pp[lane * NE + (iv[j] ^ (lane & 31))] * inv;
        const int tok = t0 + lane;
        *reinterpret_cast<float4*>(out_wts + (size_t)tok * TOPK)
            = make_float4(ws0[0], ws0[1], ws0[2], ws0[3]);
        *reinterpret_cast<float4*>(out_wts + (size_t)tok * TOPK + 4)
            = make_float4(ws0[4], ws0[5], ws0[6], ws0[7]);
        *reinterpret_cast<float4*>(out_idx + (size_t)tok * TOPK)
            = make_float4((float)iv[0], (float)iv[1], (float)iv[2], (float)iv[3]);
        *reinterpret_cast<float4*>(out_idx + (size_t)tok * TOPK + 4)
            = make_float4((float)iv[4], (float)iv[5], (float)iv[6], (float)iv[7]);
    }
    __syncthreads();
    {
        const size_t base = (size_t)t0 * NE;
#pragma unroll
        for (int r = 0; r < (64 * NE) / BLK; ++r) {
            const int idx = r * BLK + tid;
            const int t = idx >> 6, e = idx & 63;
            out_probs[base + idx] = pp[t * NE + (e ^ (t & 31))] * pinv[t];
        }
    }
}

extern "C" void kernel_launch(void* const* d_in, const int* in_sizes, int n_in,
                              void* d_out, int out_size, void* d_ws, size_t ws_size,
                              hipStream_t stream)
{
    const float* h  = (const float*)d_in[0];
    const float* w  = (const float*)d_in[1];
    const float* cs = (const float*)d_in[2];
    const float* cb = (const float*)d_in[3];
    float* outp = (float*)d_out;
    const int T = in_sizes[0] / ND;   // 16384 tokens

    const size_t need = (size_t)NPAN * T * NE * sizeof(float);  // 25.2 MB

    if (ws_size >= need) {
        float* wsp = (float*)d_ws;
        dim3 g1(T / TT, NPAN);        // 128 x 6 = 768 blocks
        hipLaunchKernelGGL(gemm_panel_kernel, g1, dim3(BLK), 0, stream,
                           h, w, wsp, T);
        hipLaunchKernelGGL(combine_kernel, dim3(T / 64), dim3(BLK), 0, stream,
                           wsp, cs, cb, outp, T);
    } else {
        hipLaunchKernelGGL(gate_single_kernel, dim3(T / 64), dim3(BLK), 0, stream,
                           h, w, cs, cb, outp, T);
    }
}